// Round 1
// baseline (55.676 us; speedup 1.0000x reference)
//
#include <hip/hip_runtime.h>
#include <math.h>

#define NATOMS 32
#define NMOL 64
#define NPAIRS 496          // 32 choose 2
#define FEAT 384            // 64 radial + 320 angular
#define RCRf 5.2f
#define RCAf 3.5f

__global__ __launch_bounds__(256) void aev_kernel(const int* __restrict__ species,
                                                  const float* __restrict__ coords,
                                                  float* __restrict__ out) {
    const int bid = blockIdx.x;          // n*32 + i
    const int n = bid >> 5;
    const int i = bid & 31;
    const int tid = threadIdx.x;

    __shared__ float cxs[NATOMS], cys[NATOMS], czs[NATOMS];
    __shared__ int   sp[NATOMS];
    __shared__ float dvx[NATOMS], dvy[NATOMS], dvz[NATOMS], dd[NATOMS], fca[NATOMS];
    __shared__ float acc[FEAT];

    if (tid < NATOMS) {
        const float* c = coords + (size_t)(n*NATOMS + tid)*3;
        cxs[tid] = c[0]; cys[tid] = c[1]; czs[tid] = c[2];
        sp[tid]  = species[n*NATOMS + tid];
    }
    for (int f = tid; f < FEAT; f += blockDim.x) acc[f] = 0.f;
    __syncthreads();

    if (tid < NATOMS) {
        float dx = cxs[tid]-cxs[i], dy = cys[tid]-cys[i], dz = czs[tid]-czs[i];
        float d2 = dx*dx + dy*dy + dz*dz;
        float d  = sqrtf(d2 > 0.f ? d2 : 1.0f);   // matches ref's where(d2>0,d2,1) guard
        dvx[tid] = dx; dvy[tid] = dy; dvz[tid] = dz; dd[tid] = d;
        fca[tid] = (tid != i && d <= RCAf) ? (0.5f*cosf((float)M_PI*d/RCAf) + 0.5f) : 0.f;

        // ---- radial part: this thread owns neighbor j = tid ----
        if (tid != i && d <= RCRf) {
            float fcr = 0.5f*cosf((float)M_PI*d/RCRf) + 0.5f;
            int base = sp[tid] * 16;
            #pragma unroll
            for (int r = 0; r < 16; ++r) {
                float sh = 0.9f + 0.26875f * (float)r;   // linspace(0.9,5.2,17)[:-1]
                float dm = d - sh;
                atomicAdd(&acc[base + r], 0.25f * expf(-16.f * dm * dm) * fcr);
            }
        }
    }
    __syncthreads();

    // angular shift constants: SHF_Z[z] = z*pi/8 + pi/16
    float czv[8], szv[8];
    #pragma unroll
    for (int z = 0; z < 8; ++z) {
        float a = (float)z * ((float)M_PI / 8.f) + (float)M_PI / 16.f;
        czv[z] = cosf(a);
        szv[z] = sinf(a);
    }

    // ---- angular part: pairs (j<k), both != i, both inside RCA ----
    for (int p = tid; p < NPAIRS; p += blockDim.x) {
        int j = 0, rem = p;
        while (rem >= 31 - j) { rem -= 31 - j; ++j; }
        int k = j + 1 + rem;
        if (j == i || k == i) continue;
        float fc = fca[j] * fca[k];          // 0 if either outside cutoff
        if (fc <= 0.f) continue;
        float dj = dd[j], dk = dd[k];
        float dot = dvx[j]*dvx[k] + dvy[j]*dvy[k] + dvz[j]*dvz[k];
        float c = 0.95f * dot / (dj * dk);
        c = fminf(0.95f, fmaxf(-0.95f, c));
        float s = sqrtf(1.f - c*c);          // sin(acos(c)), theta in [0,pi]
        float dmean = 0.5f * (dj + dk);
        int sa = sp[j], sb = sp[k];
        int lo = sa < sb ? sa : sb;
        int hi = sa < sb ? sb : sa;
        int pidx = ((lo * (9 - lo)) >> 1) + (hi - lo);   // triu index, S=4
        int base = 64 + pidx * 32;
        #pragma unroll
        for (int a = 0; a < 4; ++a) {
            float sh = 0.9f + 0.65f * (float)a;          // linspace(0.9,3.5,5)[:-1]
            float dm = dmean - sh;
            float f2c = expf(-8.f * dm * dm) * 2.f * fc;
            #pragma unroll
            for (int z = 0; z < 8; ++z) {
                float cd = c * czv[z] + s * szv[z];      // cos(theta - SHF_Z[z])
                float x  = 0.5f * (1.f + cd);
                float x2 = x*x, x4 = x2*x2, x8 = x4*x4, x16 = x8*x8;
                atomicAdd(&acc[base + a*8 + z], f2c * (x16 * x16));  // ^ZETA=32
            }
        }
    }
    __syncthreads();

    // ---- write outputs ----
    if (tid == 0) out[bid] = (float)sp[i];               // output 0: species as f32
    float* o = out + NMOL*NATOMS + (size_t)bid * FEAT;   // output 1: aev
    for (int f = tid; f < FEAT; f += blockDim.x) o[f] = acc[f];
}

extern "C" void kernel_launch(void* const* d_in, const int* in_sizes, int n_in,
                              void* d_out, int out_size, void* d_ws, size_t ws_size,
                              hipStream_t stream) {
    const int*   species = (const int*)d_in[0];
    const float* coords  = (const float*)d_in[1];
    float*       out     = (float*)d_out;
    aev_kernel<<<NMOL * NATOMS, 256, 0, stream>>>(species, coords, out);
}

// Round 3
// 52.314 us; speedup vs baseline: 1.0643x; 1.0643x over previous
//
#include <hip/hip_runtime.h>
#include <math.h>

#define NATOMS 32
#define NMOL   64
#define RCRf 5.2f
#define RCAf 3.5f

// One block per (molecule n, center atom i). 256 threads:
//  - wave 0: setup (dv, d, fc) + deterministic ballot-compaction of valid (j<k) pairs
//  - phase 3: feature ownership, register accumulation, zero atomics.
//    thread tid        -> angular feature tid        (pidx = tid>>5 in 0..7)
//    thread tid < 64   -> also angular feature 256+tid (pidx 8..9, same a,z)
//    thread 64..127    -> also radial feature tid-64 (species = (tid-64)>>4, shift = tid&15)
__global__ __launch_bounds__(256) void aev_kernel(const int* __restrict__ species,
                                                  const float* __restrict__ coords,
                                                  float* __restrict__ out) {
    const int bid = blockIdx.x;
    const int n = bid >> 5;
    const int i = bid & 31;
    const int tid = threadIdx.x;

    __shared__ float s_dvx[NATOMS], s_dvy[NATOMS], s_dvz[NATOMS];
    __shared__ float s_dd[NATOMS], s_fca[NATOMS], s_fcr[NATOMS];
    __shared__ int   s_sp[NATOMS];
    __shared__ int   s_plist[512];   // packed: jk | (pair_species_idx << 10)
    __shared__ int   s_np;

    // ---------- wave 0: setup + ordered compaction ----------
    if (tid < 64) {
        float fca_v = 0.f;
        int   sp_v  = 0;
        if (tid < NATOMS) {
            const float* cb = coords + (size_t)n * NATOMS * 3;
            float cx = cb[tid*3+0], cy = cb[tid*3+1], cz = cb[tid*3+2];
            float ix = cb[i*3+0],   iy = cb[i*3+1],   iz = cb[i*3+2];
            float dx = cx-ix, dy = cy-iy, dz = cz-iz;
            float d2 = dx*dx + dy*dy + dz*dz;
            float d  = sqrtf(d2 > 0.f ? d2 : 1.f);     // ref's where(d2>0,d2,1) guard
            sp_v = species[n*NATOMS + tid];
            bool self = (tid == i);
            float fr = (!self && d <= RCRf) ? (0.5f*__cosf(((float)M_PI/RCRf)*d) + 0.5f) : 0.f;
            fca_v    = (!self && d <= RCAf) ? (0.5f*__cosf(((float)M_PI/RCAf)*d) + 0.5f) : 0.f;
            s_dvx[tid]=dx; s_dvy[tid]=dy; s_dvz[tid]=dz;
            s_dd[tid]=d; s_fca[tid]=fca_v; s_fcr[tid]=fr; s_sp[tid]=sp_v;
        }
        // compact valid pairs (j<k, both inside RCA, both != i via fca==0)
        int base = 0;
        const int lane = tid;
        for (int it = 0; it < 16; ++it) {
            int jk = it*64 + lane;           // jk = j*32 + k
            int j = jk >> 5, k = jk & 31;
            // ALL shuffles in full-wave-active context (ds_bpermute does not
            // supply data from exec-masked-off source lanes — R2's bug).
            float fj = __shfl(fca_v, j);
            float fk = __shfl(fca_v, k);
            int   sj = __shfl(sp_v, j);
            int   sk = __shfl(sp_v, k);
            bool valid = (j < k) && (fj > 0.f) && (fk > 0.f);
            unsigned long long mask = __ballot(valid);
            int pos = base + __popcll(mask & ((1ull << lane) - 1ull));
            if (valid) {
                int lo = min(sj, sk), hi = max(sj, sk);
                int px = ((lo*(9-lo)) >> 1) + (hi - lo);   // triu pair index, S=4
                s_plist[pos] = jk | (px << 10);
            }
            base += __popcll(mask);
        }
        if (lane == 0) s_np = base;
    }
    __syncthreads();

    // ---------- phase 3: feature-ownership accumulation ----------
    const int np = s_np;
    const int pidx0 = tid >> 5;
    const int a = (tid >> 3) & 3;
    const int z = tid & 7;
    const float sha = 0.9f + 0.65f * (float)a;                          // SHF_A
    const float zang = (float)z * ((float)M_PI/8.f) + (float)M_PI/16.f; // SHF_Z
    const float czv = __cosf(zang), szv = __sinf(zang);
    const bool dual = (tid < 64);
    const int pidx1 = 8 + pidx0;   // valid only when dual

    float acc0 = 0.f, acc1 = 0.f;
    for (int p = 0; p < np; ++p) {
        int e = s_plist[p];
        int px = e >> 10;
        bool m0 = (px == pidx0);
        bool m1 = dual && (px == pidx1);
        if (m0 | m1) {
            int j = (e >> 5) & 31, k = e & 31;
            float djx=s_dvx[j], djy=s_dvy[j], djz=s_dvz[j];
            float dkx=s_dvx[k], dky=s_dvy[k], dkz=s_dvz[k];
            float dj = s_dd[j], dk = s_dd[k];
            float fc2 = 2.f * s_fca[j] * s_fca[k];
            float dot = djx*dkx + djy*dky + djz*dkz;
            float c = 0.95f * dot * __builtin_amdgcn_rcpf(dj * dk);
            c = fminf(0.95f, fmaxf(-0.95f, c));
            float s = sqrtf(1.f - c*c);                 // sin(acos(c))
            float dm = 0.5f*(dj + dk) - sha;
            float f2c = __expf(-8.f*dm*dm) * fc2;
            float cd = c*czv + s*szv;                   // cos(theta - SHF_Z[z])
            float x  = 0.5f + 0.5f*cd;
            float x2=x*x, x4=x2*x2, x8=x4*x4, x16=x8*x8;
            float t = f2c * (x16*x16);                  // ^ZETA=32
            if (m0) acc0 += t; else acc1 += t;
        }
    }

    float racc = 0.f;
    if (tid >= 64 && tid < 128) {
        int rs = (tid - 64) >> 4;           // species bucket
        float shr = 0.9f + 0.26875f * (float)(tid & 15);   // SHF_R
        #pragma unroll 4
        for (int j = 0; j < NATOMS; ++j) {
            float d = s_dd[j], fr = s_fcr[j];           // fr==0 encodes mask (j==i, d>RCR)
            float dmr = d - shr;
            float g = 0.25f * __expf(-16.f*dmr*dmr) * fr;
            racc += (s_sp[j] == rs) ? g : 0.f;
        }
    }

    // ---------- writes ----------
    float* oa = out + NMOL*NATOMS + (size_t)bid * 384;
    oa[64 + tid] = acc0;
    if (dual) oa[320 + tid] = acc1;
    if (tid >= 64 && tid < 128) oa[tid - 64] = racc;
    if (tid == 128) out[bid] = (float)s_sp[i];
}

extern "C" void kernel_launch(void* const* d_in, const int* in_sizes, int n_in,
                              void* d_out, int out_size, void* d_ws, size_t ws_size,
                              hipStream_t stream) {
    const int*   species = (const int*)d_in[0];
    const float* coords  = (const float*)d_in[1];
    float*       out     = (float*)d_out;
    aev_kernel<<<NMOL * NATOMS, 256, 0, stream>>>(species, coords, out);
}

// Round 4
// 39.305 us; speedup vs baseline: 1.4165x; 1.3310x over previous
//
#include <hip/hip_runtime.h>
#include <math.h>

#define NATOMS 32
#define NMOL   64
#define MAXP   468     // >= C(31,2)=465 candidate pairs
#define RCRf 5.2f
#define RCAf 3.5f

// One block per (molecule n, center atom i). 256 threads.
// Phase 1 (wave 0): atom setup + deterministic ballot-compaction of valid pairs.
// Phase 2 (all threads): per-pair precompute of (cos, sin, dmean, 2*fc) -> LDS float4.
// Phase 3 (feature ownership): each lane owns (px,a,z); scans compact list with a
//   1xb32 + 1xb128 broadcast-read, ~12-VALU body. Zero atomics, register acc.
//   tid       -> angular feature tid (pidx0 = tid>>5 in 0..7)
//   tid < 64  -> also angular feature 256+tid (pidx 8..9)
//   tid 64-127-> also radial feature tid-64 (species (tid-64)>>4, shift tid&15)
__global__ __launch_bounds__(256) void aev_kernel(const int* __restrict__ species,
                                                  const float* __restrict__ coords,
                                                  float* __restrict__ out) {
    const int bid = blockIdx.x;
    const int n = bid >> 5;
    const int i = bid & 31;
    const int tid = threadIdx.x;

    __shared__ float4 s_atom[NATOMS];          // dvx, dvy, dvz, d
    __shared__ float  s_fca[NATOMS], s_fcr[NATOMS];
    __shared__ int    s_sp[NATOMS];
    __shared__ int    s_pe[MAXP];              // jk, later jk | px<<10
    __shared__ float4 s_pd[MAXP];              // c, s, dmean, fc2
    __shared__ int    s_np;

    // ---------- phase 1: wave 0 ----------
    if (tid < 64) {
        float fca_v = 0.f;
        if (tid < NATOMS) {
            const float* cb = coords + (size_t)n * NATOMS * 3;
            float dx = cb[tid*3+0] - cb[i*3+0];
            float dy = cb[tid*3+1] - cb[i*3+1];
            float dz = cb[tid*3+2] - cb[i*3+2];
            float d2 = dx*dx + dy*dy + dz*dz;
            float d  = sqrtf(d2 > 0.f ? d2 : 1.f);   // ref's where(d2>0,d2,1) guard
            int   sv = species[n*NATOMS + tid];
            bool self = (tid == i);
            float fr = (!self && d <= RCRf) ? (0.5f*__cosf(((float)M_PI/RCRf)*d) + 0.5f) : 0.f;
            fca_v    = (!self && d <= RCAf) ? (0.5f*__cosf(((float)M_PI/RCAf)*d) + 0.5f) : 0.f;
            s_atom[tid] = make_float4(dx, dy, dz, d);
            s_fca[tid] = fca_v; s_fcr[tid] = fr; s_sp[tid] = sv;
        }
        // deterministic compaction; ALL shuffles in full-wave-active context
        int base = 0;
        const int lane = tid;
        for (int it = 0; it < 16; ++it) {
            int jk = it*64 + lane;               // jk = j*32 + k
            int j = jk >> 5, k = jk & 31;
            float fj = __shfl(fca_v, j);
            float fk = __shfl(fca_v, k);
            bool valid = (j < k) && (fj > 0.f) && (fk > 0.f);
            unsigned long long mask = __ballot(valid);
            int pos = base + __popcll(mask & ((1ull << lane) - 1ull));
            if (valid) s_pe[pos] = jk;
            base += __popcll(mask);
        }
        if (lane == 0) s_np = base;
    }
    __syncthreads();

    const int np = s_np;

    // ---------- phase 2: all threads, per-pair precompute ----------
    for (int p = tid; p < np; p += 256) {
        int jk = s_pe[p];
        int j = jk >> 5, k = jk & 31;
        float4 aj = s_atom[j], ak = s_atom[k];
        float fc2 = 2.f * s_fca[j] * s_fca[k];
        float dot = aj.x*ak.x + aj.y*ak.y + aj.z*ak.z;
        float c = 0.95f * dot * __builtin_amdgcn_rcpf(aj.w * ak.w);
        c = fminf(0.95f, fmaxf(-0.95f, c));
        float s = sqrtf(1.f - c*c);              // sin(acos(c)), theta in [0,pi]
        float dmean = 0.5f * (aj.w + ak.w);
        int sj = s_sp[j], sk = s_sp[k];
        int lo = min(sj, sk), hi = max(sj, sk);
        int px = ((lo*(9-lo)) >> 1) + (hi - lo); // triu pair index, S=4
        s_pd[p] = make_float4(c, s, dmean, fc2);
        s_pe[p] = jk | (px << 10);
    }
    __syncthreads();

    // ---------- phase 3: feature-ownership scan ----------
    const int pidx0 = tid >> 5;
    const int a = (tid >> 3) & 3;
    const int z = tid & 7;
    const float sha = 0.9f + 0.65f * (float)a;                          // SHF_A
    const float zang = (float)z * ((float)M_PI/8.f) + (float)M_PI/16.f; // SHF_Z
    const float czv = __cosf(zang), szv = __sinf(zang);
    const bool dual = (tid < 64);
    const int pidx1 = 8 + pidx0;

    float acc0 = 0.f, acc1 = 0.f;
    for (int p = 0; p < np; ++p) {
        int e = s_pe[p];
        int px = e >> 10;
        bool m0 = (px == pidx0);
        bool m1 = dual && (px == pidx1);
        if (m0 | m1) {
            float4 pd = s_pd[p];                 // broadcast ds_read_b128
            float dm = pd.z - sha;
            float f2c = __expf(-8.f*dm*dm) * pd.w;
            float cd = pd.x*czv + pd.y*szv;      // cos(theta - SHF_Z[z])
            float x  = 0.5f + 0.5f*cd;
            float x2=x*x, x4=x2*x2, x8=x4*x4, x16=x8*x8;
            float t = f2c * (x16*x16);           // ^ZETA=32
            if (m0) acc0 += t; else acc1 += t;
        }
    }

    float racc = 0.f;
    if (tid >= 64 && tid < 128) {
        int rs = (tid - 64) >> 4;
        float shr = 0.9f + 0.26875f * (float)(tid & 15);   // SHF_R
        #pragma unroll 4
        for (int j = 0; j < NATOMS; ++j) {
            float d = s_atom[j].w, fr = s_fcr[j];  // fr==0 encodes mask
            float dmr = d - shr;
            racc += (s_sp[j] == rs) ? 0.25f * __expf(-16.f*dmr*dmr) * fr : 0.f;
        }
    }

    // ---------- writes ----------
    float* oa = out + NMOL*NATOMS + (size_t)bid * 384;
    oa[64 + tid] = acc0;
    if (dual) oa[320 + tid] = acc1;
    if (tid >= 64 && tid < 128) oa[tid - 64] = racc;
    if (tid == 128) out[bid] = (float)s_sp[i];
}

extern "C" void kernel_launch(void* const* d_in, const int* in_sizes, int n_in,
                              void* d_out, int out_size, void* d_ws, size_t ws_size,
                              hipStream_t stream) {
    const int*   species = (const int*)d_in[0];
    const float* coords  = (const float*)d_in[1];
    float*       out     = (float*)d_out;
    aev_kernel<<<NMOL * NATOMS, 256, 0, stream>>>(species, coords, out);
}

// Round 5
// 17.140 us; speedup vs baseline: 3.2483x; 2.2932x over previous
//
#include <hip/hip_runtime.h>
#include <math.h>

#define NATOMS 32
#define NMOL   64
#define NPAIRS 496     // C(32,2)
#define MAXP   466
#define RCRf 5.2f
#define RCAf 3.5f

// One block per (molecule n, center atom i). 384 threads (6 waves).
// A: tid<32 computes per-atom dv/d/fc/species into LDS.
// B: each thread decodes candidate pair p=tid (+384), computes pair data once,
//    histograms species-pair bucket px (10 LDS counters).
// C: thread 0 exclusive-scans the 10 counts.
// D: pairs placed bucket-sorted into s_pd via LDS atomic slot allocation.
// E: tid<320 owns angular feature (bucket=tid>>5, a, z) and scans ONLY its
//    bucket (no match test, broadcast b128 reads, unroll x2). tid 320..383
//    own the 64 radial features. Zero global atomics, register accumulation.
__global__ __launch_bounds__(384) void aev_kernel(const int* __restrict__ species,
                                                  const float* __restrict__ coords,
                                                  float* __restrict__ out) {
    const int bid = blockIdx.x;
    const int n = bid >> 5;
    const int i = bid & 31;
    const int tid = threadIdx.x;

    __shared__ float4 s_atom[NATOMS];            // dvx, dvy, dvz, d
    __shared__ float  s_fca[NATOMS], s_fcr[NATOMS];
    __shared__ int    s_sp[NATOMS];
    __shared__ float4 s_pd[MAXP];                // bucket-sorted: c, sin, dmean, fc2
    __shared__ int    s_cnt[10], s_base[10], s_ofs[10];

    // ---------- phase A ----------
    if (tid < 10) s_cnt[tid] = 0;
    if (tid < NATOMS) {
        const float* cb = coords + (size_t)n * NATOMS * 3;
        float dx = cb[tid*3+0] - cb[i*3+0];
        float dy = cb[tid*3+1] - cb[i*3+1];
        float dz = cb[tid*3+2] - cb[i*3+2];
        float d2 = dx*dx + dy*dy + dz*dz;
        float d  = sqrtf(d2 > 0.f ? d2 : 1.f);   // ref's where(d2>0,d2,1) guard
        bool self = (tid == i);
        s_fcr[tid] = (!self && d <= RCRf) ? (0.5f*__cosf(((float)M_PI/RCRf)*d) + 0.5f) : 0.f;
        s_fca[tid] = (!self && d <= RCAf) ? (0.5f*__cosf(((float)M_PI/RCAf)*d) + 0.5f) : 0.f;
        s_atom[tid] = make_float4(dx, dy, dz, d);
        s_sp[tid]   = species[n*NATOMS + tid];
    }
    __syncthreads();

    // ---------- phase B: pair compute + histogram ----------
    float4 pd0, pd1;
    int px0 = -1, px1 = -1;
    #pragma unroll
    for (int rep = 0; rep < 2; ++rep) {
        int p = tid + rep*384;
        if (p < NPAIRS) {
            // closed-form triangular decode: off(j) = j*(63-j)/2
            float t = sqrtf((float)(3969 - 8*p));
            int j = (int)((63.0f - t) * 0.5f);
            if (j*(63-j)/2 > p) --j;                 // float-rounding fixups
            if ((j+1)*(62-j)/2 <= p) ++j;
            int k = p - j*(63-j)/2 + j + 1;
            float fc2 = 2.f * s_fca[j] * s_fca[k];
            if (fc2 > 0.f) {                          // both in RCA, both != i
                float4 aj = s_atom[j], ak = s_atom[k];
                float dot = aj.x*ak.x + aj.y*ak.y + aj.z*ak.z;
                float c = 0.95f * dot * __builtin_amdgcn_rcpf(aj.w * ak.w);
                c = fminf(0.95f, fmaxf(-0.95f, c));
                float s = sqrtf(1.f - c*c);           // sin(acos(c))
                float dmean = 0.5f * (aj.w + ak.w);
                int sj = s_sp[j], sk = s_sp[k];
                int lo = min(sj, sk), hi = max(sj, sk);
                int px = ((lo*(9-lo)) >> 1) + (hi - lo);  // triu pair index, S=4
                if (rep == 0) { pd0 = make_float4(c, s, dmean, fc2); px0 = px; }
                else          { pd1 = make_float4(c, s, dmean, fc2); px1 = px; }
                atomicAdd(&s_cnt[px], 1);
            }
        }
    }
    __syncthreads();

    // ---------- phase C: exclusive scan (10 values) ----------
    if (tid == 0) {
        int run = 0;
        #pragma unroll
        for (int b = 0; b < 10; ++b) { s_base[b] = run; s_ofs[b] = run; run += s_cnt[b]; }
    }
    __syncthreads();

    // ---------- phase D: bucket-sorted placement ----------
    if (px0 >= 0) s_pd[atomicAdd(&s_ofs[px0], 1)] = pd0;
    if (px1 >= 0) s_pd[atomicAdd(&s_ofs[px1], 1)] = pd1;
    __syncthreads();

    // ---------- phase E: per-feature accumulation ----------
    float* oa = out + NMOL*NATOMS + (size_t)bid * 384;

    if (tid < 320) {
        const int b = tid >> 5;
        const int a = (tid >> 3) & 3;
        const int z = tid & 7;
        const float sha  = 0.9f + 0.65f * (float)a;                          // SHF_A
        const float zang = (float)z * ((float)M_PI/8.f) + (float)M_PI/16.f;  // SHF_Z
        const float czv = __cosf(zang), szv = __sinf(zang);
        const int p0 = s_base[b];
        const int pe = p0 + s_cnt[b];

        float acc = 0.f;
        int p = p0;
        for (; p + 1 < pe; p += 2) {                 // unroll x2: pipeline b128 loads
            float4 d0 = s_pd[p];
            float4 d1 = s_pd[p+1];
            float dm0 = d0.z - sha;
            float f0  = __expf(-8.f*dm0*dm0) * d0.w;
            float cd0 = d0.x*czv + d0.y*szv;
            float x0  = 0.5f + 0.5f*cd0;
            float q0 = x0*x0; q0 *= q0; q0 *= q0; q0 *= q0; q0 *= q0;  // ^32
            acc += f0 * q0;
            float dm1 = d1.z - sha;
            float f1  = __expf(-8.f*dm1*dm1) * d1.w;
            float cd1 = d1.x*czv + d1.y*szv;
            float x1  = 0.5f + 0.5f*cd1;
            float q1 = x1*x1; q1 *= q1; q1 *= q1; q1 *= q1; q1 *= q1;
            acc += f1 * q1;
        }
        if (p < pe) {
            float4 d0 = s_pd[p];
            float dm0 = d0.z - sha;
            float f0  = __expf(-8.f*dm0*dm0) * d0.w;
            float cd0 = d0.x*czv + d0.y*szv;
            float x0  = 0.5f + 0.5f*cd0;
            float q0 = x0*x0; q0 *= q0; q0 *= q0; q0 *= q0; q0 *= q0;
            acc += f0 * q0;
        }
        oa[64 + tid] = acc;
    } else {
        const int f  = tid - 320;
        const int rs = f >> 4;
        const float shr = 0.9f + 0.26875f * (float)(f & 15);   // SHF_R
        float racc = 0.f;
        #pragma unroll 8
        for (int j = 0; j < NATOMS; ++j) {
            float d = s_atom[j].w, fr = s_fcr[j];    // fr==0 encodes mask
            float dmr = d - shr;
            racc += (s_sp[j] == rs) ? 0.25f * __expf(-16.f*dmr*dmr) * fr : 0.f;
        }
        oa[f] = racc;
        if (f == 0) out[bid] = (float)s_sp[i];       // output 0: species
    }
}

extern "C" void kernel_launch(void* const* d_in, const int* in_sizes, int n_in,
                              void* d_out, int out_size, void* d_ws, size_t ws_size,
                              hipStream_t stream) {
    const int*   species = (const int*)d_in[0];
    const float* coords  = (const float*)d_in[1];
    float*       out     = (float*)d_out;
    aev_kernel<<<NMOL * NATOMS, 384, 0, stream>>>(species, coords, out);
}